// Round 2
// baseline (3108.536 us; speedup 1.0000x reference)
//
#include <hip/hip_runtime.h>

// Multiscale Residual VQ (VAR-style), MI355X gfx950.
// Round 2: fix PHI_IDX tie-breaks (si=2 -> phi1, si=7 -> phi3; exact-arith
// ties in linspace(1/12,11/12,4) break on the last ulp of float64).
// All-fp32 VALU implementation, accuracy-first.

#define NB 16      // batch
#define NL 512     // seq len
#define ND 512     // dim
#define NCB 4096   // codebook

__device__ __forceinline__ unsigned long long pack_dist(float d, int n) {
    unsigned u = __float_as_uint(d);
    u = (u & 0x80000000u) ? ~u : (u | 0x80000000u);   // monotone total order
    return ((unsigned long long)u << 32) | (unsigned)n; // tie -> lowest idx (np argmin)
}

// e_sq[c] = sum_d embed[c,d]^2, fp64 accumulate (one wave per code)
__global__ __launch_bounds__(256) void k_esq(const float* __restrict__ embed,
                                             float* __restrict__ esq) {
    int c = blockIdx.x * 4 + (threadIdx.x >> 6);
    int lane = threadIdx.x & 63;
    const float* row = embed + (size_t)c * ND;
    double acc = 0.0;
#pragma unroll
    for (int i = 0; i < ND / 64; ++i) {
        float v = row[lane + i * 64];
        acc += (double)v * (double)v;
    }
#pragma unroll
    for (int off = 32; off > 0; off >>= 1) acc += __shfl_down(acc, off, 64);
    if (lane == 0) esq[c] = (float)acc;
}

__global__ __launch_bounds__(256) void k_copy(const float* __restrict__ src,
                                              float* __restrict__ dst) {
    int gid = blockIdx.x * 256 + threadIdx.x;
    ((float4*)dst)[gid] = ((const float4*)src)[gid];
}

// Wt[kp][kk=k*512+din][dout] = phi_w[kp][dout][din][k]
__global__ __launch_bounds__(256) void k_transpose_w(const float* __restrict__ pw,
                                                     float* __restrict__ Wt) {
    int gid = blockIdx.x * 256 + threadIdx.x;   // 4*3*512*512 total
    int dout = gid & 511;
    int din = (gid >> 9) & 511;
    int rest = gid >> 18;       // kp*3 + k
    int k = rest % 3;
    int kp = rest / 3;
    Wt[gid] = pw[(((size_t)(kp * 512 + dout) * 512 + din) * 3) + k];
}

// z[b,j,d] = mean over block of residual (area downsample), fp64 accumulate
__global__ __launch_bounds__(256) void k_zmean(const float* __restrict__ resid,
                                               float* __restrict__ z, int s, int lg) {
    int gid = blockIdx.x * 256 + threadIdx.x;   // 16*s*512 threads
    int d = gid & 511;
    int j = (gid >> 9) & (s - 1);
    int b = gid >> (9 + lg);
    int r = NL >> lg;
    const float* p = resid + ((size_t)((b << 9) + (j << (9 - lg))) << 9) + d;
    double acc = 0.0;
#pragma unroll 4
    for (int m = 0; m < r; ++m) acc += (double)p[(size_t)m * ND];
    z[gid] = (float)(acc * (1.0 / (double)r));
}

// dist+argmin, big tiles: TM=TN=128, KB=16, 8x8 per thread. grid(ceil(M/128), 32)
__global__ __launch_bounds__(256) void k_dist_big(const float* __restrict__ z,
        const float* __restrict__ embed, const float* __restrict__ esq,
        unsigned long long* __restrict__ minbuf, int M) {
    __shared__ float As[16][128];
    __shared__ float Bs[16][128];
    __shared__ unsigned long long packs[128][17];
    int tid = threadIdx.x;
    int m0 = blockIdx.x * 128, n0 = blockIdx.y * 128;
    int tr = tid >> 4, tc = tid & 15;
    float acc[8][8] = {};
    for (int kb = 0; kb < 512; kb += 16) {
#pragma unroll
        for (int h2 = 0; h2 < 2; ++h2) {
            int f = tid + h2 * 256;
            int ml = f >> 2, kq = f & 3;
            int mg = m0 + ml;
            float4 v = make_float4(0.f, 0.f, 0.f, 0.f);
            if (mg < M) v = *(const float4*)(z + (size_t)mg * 512 + kb + kq * 4);
            As[kq * 4 + 0][ml] = v.x; As[kq * 4 + 1][ml] = v.y;
            As[kq * 4 + 2][ml] = v.z; As[kq * 4 + 3][ml] = v.w;
        }
#pragma unroll
        for (int h2 = 0; h2 < 2; ++h2) {
            int f = tid + h2 * 256;
            int nl = f >> 2, kq = f & 3;
            float4 v = *(const float4*)(embed + (size_t)(n0 + nl) * 512 + kb + kq * 4);
            Bs[kq * 4 + 0][nl] = v.x; Bs[kq * 4 + 1][nl] = v.y;
            Bs[kq * 4 + 2][nl] = v.z; Bs[kq * 4 + 3][nl] = v.w;
        }
        __syncthreads();
#pragma unroll
        for (int k = 0; k < 16; ++k) {
            float a[8], b[8];
            *(float4*)&a[0] = *(const float4*)&As[k][tr * 8];
            *(float4*)&a[4] = *(const float4*)&As[k][tr * 8 + 4];
            *(float4*)&b[0] = *(const float4*)&Bs[k][tc * 8];
            *(float4*)&b[4] = *(const float4*)&Bs[k][tc * 8 + 4];
#pragma unroll
            for (int i = 0; i < 8; ++i)
#pragma unroll
                for (int j = 0; j < 8; ++j)
                    acc[i][j] = fmaf(a[i], b[j], acc[i][j]);
        }
        __syncthreads();
    }
    float es[8];
#pragma unroll
    for (int j = 0; j < 8; ++j) es[j] = esq[n0 + tc * 8 + j];
#pragma unroll
    for (int i = 0; i < 8; ++i) {
        unsigned long long best = ~0ull;
#pragma unroll
        for (int j = 0; j < 8; ++j) {
            int n = n0 + tc * 8 + j;
            float dd = fmaf(-2.f, acc[i][j], es[j]);
            unsigned long long p = pack_dist(dd, n);
            best = p < best ? p : best;
        }
        packs[tr * 8 + i][tc] = best;
    }
    __syncthreads();
    if (tid < 128) {
        unsigned long long best = packs[tid][0];
#pragma unroll
        for (int t2 = 1; t2 < 16; ++t2) {
            unsigned long long p = packs[tid][t2];
            best = p < best ? p : best;
        }
        int mg = m0 + tid;
        if (mg < M) atomicMin(&minbuf[mg], best);
    }
}

// dist+argmin, small tiles: TM=32, TN=64, KB=32, 2x4 per thread. grid(ceil(M/32), 64)
__global__ __launch_bounds__(256) void k_dist_small(const float* __restrict__ z,
        const float* __restrict__ embed, const float* __restrict__ esq,
        unsigned long long* __restrict__ minbuf, int M) {
    __shared__ float As[32][32];
    __shared__ float Bs[32][64];
    __shared__ unsigned long long packs[32][17];
    int tid = threadIdx.x;
    int m0 = blockIdx.x * 32, n0 = blockIdx.y * 64;
    int tr = tid >> 4, tc = tid & 15;
    float acc[2][4] = {};
    for (int kb = 0; kb < 512; kb += 32) {
        {
            int ml = tid >> 3, kq = tid & 7;
            int mg = m0 + ml;
            float4 v = make_float4(0.f, 0.f, 0.f, 0.f);
            if (mg < M) v = *(const float4*)(z + (size_t)mg * 512 + kb + kq * 4);
            As[kq * 4 + 0][ml] = v.x; As[kq * 4 + 1][ml] = v.y;
            As[kq * 4 + 2][ml] = v.z; As[kq * 4 + 3][ml] = v.w;
        }
#pragma unroll
        for (int h2 = 0; h2 < 2; ++h2) {
            int f = tid + h2 * 256;
            int nl = f >> 3, kq = f & 7;
            float4 v = *(const float4*)(embed + (size_t)(n0 + nl) * 512 + kb + kq * 4);
            Bs[kq * 4 + 0][nl] = v.x; Bs[kq * 4 + 1][nl] = v.y;
            Bs[kq * 4 + 2][nl] = v.z; Bs[kq * 4 + 3][nl] = v.w;
        }
        __syncthreads();
#pragma unroll
        for (int k = 0; k < 32; ++k) {
            float a0 = As[k][tr * 2], a1 = As[k][tr * 2 + 1];
            float4 b4 = *(const float4*)&Bs[k][tc * 4];
            acc[0][0] = fmaf(a0, b4.x, acc[0][0]);
            acc[0][1] = fmaf(a0, b4.y, acc[0][1]);
            acc[0][2] = fmaf(a0, b4.z, acc[0][2]);
            acc[0][3] = fmaf(a0, b4.w, acc[0][3]);
            acc[1][0] = fmaf(a1, b4.x, acc[1][0]);
            acc[1][1] = fmaf(a1, b4.y, acc[1][1]);
            acc[1][2] = fmaf(a1, b4.z, acc[1][2]);
            acc[1][3] = fmaf(a1, b4.w, acc[1][3]);
        }
        __syncthreads();
    }
#pragma unroll
    for (int i = 0; i < 2; ++i) {
        unsigned long long best = ~0ull;
#pragma unroll
        for (int j = 0; j < 4; ++j) {
            int n = n0 + tc * 4 + j;
            float dd = fmaf(-2.f, acc[i][j], esq[n]);
            unsigned long long p = pack_dist(dd, n);
            best = p < best ? p : best;
        }
        packs[tr * 2 + i][tc] = best;
    }
    __syncthreads();
    if (tid < 32) {
        unsigned long long best = packs[tid][0];
#pragma unroll
        for (int t2 = 1; t2 < 16; ++t2) {
            unsigned long long p = packs[tid][t2];
            best = p < best ? p : best;
        }
        int mg = m0 + tid;
        if (mg < M) atomicMin(&minbuf[mg], best);
    }
}

// h[b,t,d] = linear (half-pixel, clamped) upsample of embed[idx[b,:]] from s to 512
__global__ __launch_bounds__(256) void k_upsample(const unsigned long long* __restrict__ minbuf,
        const float* __restrict__ embed, float* __restrict__ h, int s, float scale) {
    int gid = blockIdx.x * 256 + threadIdx.x;   // one float4 each
    int d4 = (gid & 127) << 2;
    int bt = gid >> 7;
    int b = bt >> 9, t = bt & 511;
    float u = ((float)t + 0.5f) * scale - 0.5f;  // scale = s/512 (pow2 -> exact)
    float fl = floorf(u);
    float w = u - fl;
    int i0 = (int)fl;
    int i1 = i0 + 1;
    i0 = min(max(i0, 0), s - 1);
    i1 = min(max(i1, 0), s - 1);
    int base = b * s;
    int idx0 = (int)(unsigned)(minbuf[base + i0]);
    int idx1 = (int)(unsigned)(minbuf[base + i1]);
    float4 e0 = *(const float4*)(embed + (size_t)idx0 * 512 + d4);
    float4 e1 = *(const float4*)(embed + (size_t)idx1 * 512 + d4);
    float om = 1.0f - w;
    float4 o;
    o.x = om * e0.x + w * e1.x;
    o.y = om * e0.y + w * e1.y;
    o.z = om * e0.z + w * e1.z;
    o.w = om * e0.w + w * e1.w;
    *(float4*)(h + (size_t)gid * 4) = o;
}

// resid -= 0.5*h + 0.5*(conv(h)+bias). GEMM [8192x1536]x[1536x64tile].
// TM=128, TN=64, KB=16, 8x4 per thread. grid(64, 8)
__global__ __launch_bounds__(256) void k_conv(const float* __restrict__ h,
        const float* __restrict__ Wt, const float* __restrict__ bias,
        float* __restrict__ resid) {
    __shared__ float As[16][128];
    __shared__ float Bs[16][64];
    int tid = threadIdx.x;
    int m0 = blockIdx.x * 128;   // m = b*512 + t, 128 | 512 -> single batch
    int n0 = blockIdx.y * 64;
    int bb = m0 >> 9;
    int t0 = m0 & 511;
    int tr = tid >> 4, tc = tid & 15;
    float acc[8][4] = {};
    for (int kb = 0; kb < 1536; kb += 16) {
        int kconv = kb >> 9;      // 0,1,2 (KB | 512 keeps block in one shift)
        int din0 = kb & 511;
#pragma unroll
        for (int h2 = 0; h2 < 2; ++h2) {
            int f = tid + h2 * 256;
            int ml = f >> 2, kq = f & 3;
            int tt = t0 + ml + kconv - 1;
            float4 v = make_float4(0.f, 0.f, 0.f, 0.f);
            if (tt >= 0 && tt < 512)   // zero pad at batch edges
                v = *(const float4*)(h + (((size_t)(bb << 9) + tt) << 9) + din0 + kq * 4);
            As[kq * 4 + 0][ml] = v.x; As[kq * 4 + 1][ml] = v.y;
            As[kq * 4 + 2][ml] = v.z; As[kq * 4 + 3][ml] = v.w;
        }
        {
            int kl = tid >> 4, nq = tid & 15;
            float4 v = *(const float4*)(Wt + (size_t)(kb + kl) * 512 + n0 + nq * 4);
            *(float4*)&Bs[kl][nq * 4] = v;
        }
        __syncthreads();
#pragma unroll
        for (int k = 0; k < 16; ++k) {
            float a[8];
            float4 b4 = *(const float4*)&Bs[k][tc * 4];
            *(float4*)&a[0] = *(const float4*)&As[k][tr * 8];
            *(float4*)&a[4] = *(const float4*)&As[k][tr * 8 + 4];
#pragma unroll
            for (int i = 0; i < 8; ++i) {
                acc[i][0] = fmaf(a[i], b4.x, acc[i][0]);
                acc[i][1] = fmaf(a[i], b4.y, acc[i][1]);
                acc[i][2] = fmaf(a[i], b4.z, acc[i][2]);
                acc[i][3] = fmaf(a[i], b4.w, acc[i][3]);
            }
        }
        __syncthreads();
    }
    float4 bi = *(const float4*)(bias + n0 + tc * 4);
#pragma unroll
    for (int i = 0; i < 8; ++i) {
        size_t off = ((size_t)(m0 + tr * 8 + i) << 9) + n0 + tc * 4;
        float4 rv = *(float4*)(resid + off);
        float4 hv = *(const float4*)(h + off);
        rv.x -= 0.5f * hv.x + 0.5f * (acc[i][0] + bi.x);
        rv.y -= 0.5f * hv.y + 0.5f * (acc[i][1] + bi.y);
        rv.z -= 0.5f * hv.z + 0.5f * (acc[i][2] + bi.z);
        rv.w -= 0.5f * hv.w + 0.5f * (acc[i][3] + bi.w);
        *(float4*)(resid + off) = rv;
    }
}

__global__ __launch_bounds__(256) void k_final(const float* __restrict__ x,
        const float* __restrict__ resid, float* __restrict__ out) {
    int gid = blockIdx.x * 256 + threadIdx.x;
    float4 xv = ((const float4*)x)[gid];
    float4 rv = ((const float4*)resid)[gid];
    float4 o;
    o.x = xv.x - rv.x; o.y = xv.y - rv.y; o.z = xv.z - rv.z; o.w = xv.w - rv.w;
    ((float4*)out)[gid] = o;
}

extern "C" void kernel_launch(void* const* d_in, const int* in_sizes, int n_in,
                              void* d_out, int out_size, void* d_ws, size_t ws_size,
                              hipStream_t stream) {
    const float* x     = (const float*)d_in[0];
    const float* embed = (const float*)d_in[1];
    const float* pw    = (const float*)d_in[2];
    const float* pb    = (const float*)d_in[3];
    float* out = (float*)d_out;

    // ws layout (floats): resid 4194304 | zbuf 2097152 | Wt 3145728 | esq 4096 | minbuf(u64) 8192
    float* resid = (float*)d_ws;
    float* zbuf  = resid + 4194304;
    float* Wt    = zbuf + 2097152;
    float* esq   = Wt + 3145728;
    unsigned long long* minbuf = (unsigned long long*)(esq + 4096);

    k_esq<<<1024, 256, 0, stream>>>(embed, esq);
    k_copy<<<4096, 256, 0, stream>>>(x, resid);
    k_transpose_w<<<12288, 256, 0, stream>>>(pw, Wt);

    const int SCv[10] = {1, 2, 4, 8, 16, 32, 64, 128, 256, 512};
    // PHI_IDX: ticks=linspace(1/12,11/12,4); si=2 and si=7 are exact-arith ties
    // that break on the last ulp of float64 toward the HIGHER tick: {0,0,1,1,1,2,2,3,3,3}
    const int PIv[10] = {0, 0, 1, 1, 1, 2, 2, 3, 3, 3};
    for (int si = 0; si < 10; ++si) {
        int s = SCv[si];
        int M = 16 * s;
        const float* zptr = resid;   // s==512: z == residual (block size 1)
        if (s < 512) {
            int lg = __builtin_ctz((unsigned)s);
            k_zmean<<<(16 * s * 512) / 256, 256, 0, stream>>>(resid, zbuf, s, lg);
            zptr = zbuf;
        }
        hipMemsetAsync(minbuf, 0xFF, (size_t)M * 8, stream);
        if (s >= 128)
            k_dist_big<<<dim3((M + 127) / 128, 32), 256, 0, stream>>>(zptr, embed, esq, minbuf, M);
        else
            k_dist_small<<<dim3((M + 31) / 32, 64), 256, 0, stream>>>(zptr, embed, esq, minbuf, M);
        k_upsample<<<4096, 256, 0, stream>>>(minbuf, embed, out, s, (float)s / 512.0f);
        k_conv<<<dim3(64, 8), 256, 0, stream>>>(out, Wt + (size_t)PIv[si] * 1536 * 512,
                                                pb + PIv[si] * 512, resid);
    }
    k_final<<<4096, 256, 0, stream>>>(x, resid, out);
}

// Round 4
// 1722.008 us; speedup vs baseline: 1.8052x; 1.8052x over previous
//
#include <hip/hip_runtime.h>

// Multiscale Residual VQ (VAR-style), MI355X gfx950.
// Round 4: compile fix of round 3 (split2 returns by value; _Float16& can't
// bind to ext_vector elements). fp16 2-way-split MFMA (16x16x32_f16, 3 passes:
// hi*hi + (hi*lo+lo*hi)/4096) for dist (s>=16) and all Phi convs. lo pre-scaled
// by 4096 -> no fp16 denormals. Error per dot ~2^-24-grade == fp32 class
// (round-2 proved zero argmin flips there).

#define NB 16
#define NL 512
#define ND 512
#define NCB 4096

typedef _Float16 half4v __attribute__((ext_vector_type(4)));
typedef _Float16 half8v __attribute__((ext_vector_type(8)));
typedef float floatx4 __attribute__((ext_vector_type(4)));

struct HL { _Float16 h, l; };

__device__ __forceinline__ HL split2(float v) {
    HL r;
    r.h = (_Float16)v;
    r.l = (_Float16)((v - (float)r.h) * 4096.0f);
    return r;
}

__device__ __forceinline__ unsigned long long pack_dist(float d, int n) {
    unsigned u = __float_as_uint(d);
    u = (u & 0x80000000u) ? ~u : (u | 0x80000000u);   // monotone total order
    return ((unsigned long long)u << 32) | (unsigned)n; // tie -> lowest idx (np argmin)
}

// e_sq[c] = sum_d embed[c,d]^2, fp64 accumulate
__global__ __launch_bounds__(256) void k_esq(const float* __restrict__ embed,
                                             float* __restrict__ esq) {
    int c = blockIdx.x * 4 + (threadIdx.x >> 6);
    int lane = threadIdx.x & 63;
    const float* row = embed + (size_t)c * ND;
    double acc = 0.0;
#pragma unroll
    for (int i = 0; i < ND / 64; ++i) {
        float v = row[lane + i * 64];
        acc += (double)v * (double)v;
    }
#pragma unroll
    for (int off = 32; off > 0; off >>= 1) acc += __shfl_down(acc, off, 64);
    if (lane == 0) esq[c] = (float)acc;
}

__global__ __launch_bounds__(256) void k_copy(const float* __restrict__ src,
                                              float* __restrict__ dst) {
    int gid = blockIdx.x * 256 + threadIdx.x;
    ((float4*)dst)[gid] = ((const float4*)src)[gid];
}

// W split: out[kp][dout][ktap*512+din] (hi/lo fp16) from pw[kp][dout][din][ktap]
__global__ __launch_bounds__(256) void k_split_w(const float* __restrict__ pw,
        _Float16* __restrict__ Whi, _Float16* __restrict__ Wlo) {
    int gid = blockIdx.x * 256 + threadIdx.x;   // 4*512*1536
    int kk = gid % 1536;
    int rest = gid / 1536;      // kp*512 + dout
    int ktap = kk >> 9;
    int din = kk & 511;
    float v = pw[((size_t)rest * 512 + din) * 3 + ktap];
    HL r = split2(v);
    Whi[gid] = r.h;
    Wlo[gid] = r.l;
}

// z[b,j,d] = block mean of residual, fp64 accumulate (fp32 out)
__global__ __launch_bounds__(256) void k_zmean(const float* __restrict__ resid,
                                               float* __restrict__ z, int s, int lg) {
    int gid = blockIdx.x * 256 + threadIdx.x;
    int d = gid & 511;
    int j = (gid >> 9) & (s - 1);
    int b = gid >> (9 + lg);
    int r = NL >> lg;
    const float* p = resid + ((size_t)((b << 9) + (j << (9 - lg))) << 9) + d;
    double acc = 0.0;
#pragma unroll 4
    for (int m = 0; m < r; ++m) acc += (double)p[(size_t)m * ND];
    z[gid] = (float)(acc * (1.0 / (double)r));
}

// ---------------- MFMA dist: block 128m x 64n, 4 waves (2x2) each 64x32 ----------------
__global__ __launch_bounds__(256) void k_dist_mfma(const float* __restrict__ z,
        const float* __restrict__ embed, const float* __restrict__ esq,
        unsigned long long* __restrict__ minbuf) {
    __shared__ _Float16 Ah[128][40], Al[128][40], Bh[64][40], Bl[64][40];
    __shared__ unsigned long long packs[128][2];
    int tid = threadIdx.x;
    int lane = tid & 63, wave = tid >> 6;
    int wm = wave >> 1, wn = wave & 1;
    int quad = lane >> 4, l15 = lane & 15;
    int m0 = blockIdx.x * 128, n0 = blockIdx.y * 64;

    floatx4 acch[4][2], accx[4][2];
#pragma unroll
    for (int i = 0; i < 4; ++i)
#pragma unroll
        for (int j = 0; j < 2; ++j)
#pragma unroll
            for (int r = 0; r < 4; ++r) { acch[i][j][r] = 0.f; accx[i][j][r] = 0.f; }

    for (int kb = 0; kb < 512; kb += 32) {
        // stage A (128x32) from z fp32, split on the fly: 4 rounds
#pragma unroll
        for (int r = 0; r < 4; ++r) {
            int t2 = tid + r * 256;
            int row = t2 >> 3, c4 = t2 & 7;
            float4 v = *(const float4*)(z + (size_t)(m0 + row) * 512 + kb + c4 * 4);
            HL e0 = split2(v.x), e1 = split2(v.y), e2 = split2(v.z), e3 = split2(v.w);
            half4v hh, ll;
            hh[0] = e0.h; hh[1] = e1.h; hh[2] = e2.h; hh[3] = e3.h;
            ll[0] = e0.l; ll[1] = e1.l; ll[2] = e2.l; ll[3] = e3.l;
            *(half4v*)&Ah[row][c4 * 4] = hh;
            *(half4v*)&Al[row][c4 * 4] = ll;
        }
        // stage B (64x32) from embed fp32: 2 rounds
#pragma unroll
        for (int r = 0; r < 2; ++r) {
            int t2 = tid + r * 256;
            int row = t2 >> 3, c4 = t2 & 7;
            float4 v = *(const float4*)(embed + (size_t)(n0 + row) * 512 + kb + c4 * 4);
            HL e0 = split2(v.x), e1 = split2(v.y), e2 = split2(v.z), e3 = split2(v.w);
            half4v hh, ll;
            hh[0] = e0.h; hh[1] = e1.h; hh[2] = e2.h; hh[3] = e3.h;
            ll[0] = e0.l; ll[1] = e1.l; ll[2] = e2.l; ll[3] = e3.l;
            *(half4v*)&Bh[row][c4 * 4] = hh;
            *(half4v*)&Bl[row][c4 * 4] = ll;
        }
        __syncthreads();
        half8v afh[4], afl[4], bfh[2], bfl[2];
#pragma unroll
        for (int tm = 0; tm < 4; ++tm) {
            afh[tm] = *(const half8v*)&Ah[wm * 64 + tm * 16 + l15][quad * 8];
            afl[tm] = *(const half8v*)&Al[wm * 64 + tm * 16 + l15][quad * 8];
        }
#pragma unroll
        for (int tn = 0; tn < 2; ++tn) {
            bfh[tn] = *(const half8v*)&Bh[wn * 32 + tn * 16 + l15][quad * 8];
            bfl[tn] = *(const half8v*)&Bl[wn * 32 + tn * 16 + l15][quad * 8];
        }
#pragma unroll
        for (int tm = 0; tm < 4; ++tm)
#pragma unroll
            for (int tn = 0; tn < 2; ++tn) {
                acch[tm][tn] = __builtin_amdgcn_mfma_f32_16x16x32_f16(afh[tm], bfh[tn], acch[tm][tn], 0, 0, 0);
                accx[tm][tn] = __builtin_amdgcn_mfma_f32_16x16x32_f16(afh[tm], bfl[tn], accx[tm][tn], 0, 0, 0);
                accx[tm][tn] = __builtin_amdgcn_mfma_f32_16x16x32_f16(afl[tm], bfh[tn], accx[tm][tn], 0, 0, 0);
            }
        __syncthreads();
    }
    float es[2];
    es[0] = esq[n0 + wn * 32 + l15];
    es[1] = esq[n0 + wn * 32 + 16 + l15];
#pragma unroll
    for (int tm = 0; tm < 4; ++tm)
#pragma unroll
        for (int reg = 0; reg < 4; ++reg) {
            unsigned long long best = ~0ull;
#pragma unroll
            for (int tn = 0; tn < 2; ++tn) {
                float dot = acch[tm][tn][reg] + accx[tm][tn][reg] * (1.0f / 4096.0f);
                int n = n0 + wn * 32 + tn * 16 + l15;
                float dd = fmaf(-2.f, dot, es[tn]);
                unsigned long long p = pack_dist(dd, n);
                best = p < best ? p : best;
            }
#pragma unroll
            for (int off = 1; off < 16; off <<= 1) {
                unsigned long long q = __shfl_xor(best, off, 64);
                best = q < best ? q : best;
            }
            if (l15 == 0) packs[wm * 64 + tm * 16 + quad * 4 + reg][wn] = best;
        }
    __syncthreads();
    if (tid < 128) {
        unsigned long long b0 = packs[tid][0], b1 = packs[tid][1];
        unsigned long long best = b0 < b1 ? b0 : b1;
        atomicMin(&minbuf[m0 + tid], best);
    }
}

// dist small (fp32), s<=8: TM=32, TN=64, KB=32, 2x4/thread. grid(ceil(M/32), 64)
__global__ __launch_bounds__(256) void k_dist_small(const float* __restrict__ z,
        const float* __restrict__ embed, const float* __restrict__ esq,
        unsigned long long* __restrict__ minbuf, int M) {
    __shared__ float As[32][32];
    __shared__ float Bs[32][64];
    __shared__ unsigned long long packs[32][17];
    int tid = threadIdx.x;
    int m0 = blockIdx.x * 32, n0 = blockIdx.y * 64;
    int tr = tid >> 4, tc = tid & 15;
    float acc[2][4] = {};
    for (int kb = 0; kb < 512; kb += 32) {
        {
            int ml = tid >> 3, kq = tid & 7;
            int mg = m0 + ml;
            float4 v = make_float4(0.f, 0.f, 0.f, 0.f);
            if (mg < M) v = *(const float4*)(z + (size_t)mg * 512 + kb + kq * 4);
            As[kq * 4 + 0][ml] = v.x; As[kq * 4 + 1][ml] = v.y;
            As[kq * 4 + 2][ml] = v.z; As[kq * 4 + 3][ml] = v.w;
        }
#pragma unroll
        for (int h2 = 0; h2 < 2; ++h2) {
            int f = tid + h2 * 256;
            int nl = f >> 3, kq = f & 7;
            float4 v = *(const float4*)(embed + (size_t)(n0 + nl) * 512 + kb + kq * 4);
            Bs[kq * 4 + 0][nl] = v.x; Bs[kq * 4 + 1][nl] = v.y;
            Bs[kq * 4 + 2][nl] = v.z; Bs[kq * 4 + 3][nl] = v.w;
        }
        __syncthreads();
#pragma unroll
        for (int k = 0; k < 32; ++k) {
            float a0 = As[k][tr * 2], a1 = As[k][tr * 2 + 1];
            float4 b4 = *(const float4*)&Bs[k][tc * 4];
            acc[0][0] = fmaf(a0, b4.x, acc[0][0]);
            acc[0][1] = fmaf(a0, b4.y, acc[0][1]);
            acc[0][2] = fmaf(a0, b4.z, acc[0][2]);
            acc[0][3] = fmaf(a0, b4.w, acc[0][3]);
            acc[1][0] = fmaf(a1, b4.x, acc[1][0]);
            acc[1][1] = fmaf(a1, b4.y, acc[1][1]);
            acc[1][2] = fmaf(a1, b4.z, acc[1][2]);
            acc[1][3] = fmaf(a1, b4.w, acc[1][3]);
        }
        __syncthreads();
    }
#pragma unroll
    for (int i = 0; i < 2; ++i) {
        unsigned long long best = ~0ull;
#pragma unroll
        for (int j = 0; j < 4; ++j) {
            int n = n0 + tc * 4 + j;
            float dd = fmaf(-2.f, acc[i][j], esq[n]);
            unsigned long long p = pack_dist(dd, n);
            best = p < best ? p : best;
        }
        packs[tr * 2 + i][tc] = best;
    }
    __syncthreads();
    if (tid < 32) {
        unsigned long long best = packs[tid][0];
#pragma unroll
        for (int t2 = 1; t2 < 16; ++t2) {
            unsigned long long p = packs[tid][t2];
            best = p < best ? p : best;
        }
        int mg = m0 + tid;
        if (mg < M) atomicMin(&minbuf[mg], best);
    }
}

// h[b,t,d] = linear (half-pixel, clamped) upsample of embed[idx] from s to 512
__global__ __launch_bounds__(256) void k_upsample(const unsigned long long* __restrict__ minbuf,
        const float* __restrict__ embed, float* __restrict__ h, int s, float scale) {
    int gid = blockIdx.x * 256 + threadIdx.x;
    int d4 = (gid & 127) << 2;
    int bt = gid >> 7;
    int b = bt >> 9, t = bt & 511;
    float u = ((float)t + 0.5f) * scale - 0.5f;
    float fl = floorf(u);
    float w = u - fl;
    int i0 = (int)fl;
    int i1 = i0 + 1;
    i0 = min(max(i0, 0), s - 1);
    i1 = min(max(i1, 0), s - 1);
    int base = b * s;
    int idx0 = (int)(unsigned)(minbuf[base + i0]);
    int idx1 = (int)(unsigned)(minbuf[base + i1]);
    float4 e0 = *(const float4*)(embed + (size_t)idx0 * 512 + d4);
    float4 e1 = *(const float4*)(embed + (size_t)idx1 * 512 + d4);
    float om = 1.0f - w;
    float4 o;
    o.x = om * e0.x + w * e1.x;
    o.y = om * e0.y + w * e1.y;
    o.z = om * e0.z + w * e1.z;
    o.w = om * e0.w + w * e1.w;
    *(float4*)(h + (size_t)gid * 4) = o;
}

// ---------------- MFMA conv: resid -= 0.5*h + 0.5*(conv(h)+bias) ----------------
// GEMM [8192 x 1536] x [1536 x 512], kk = ktap*512+din. block 128m x 64n. grid(64,8)
__global__ __launch_bounds__(256) void k_conv_mfma(const float* __restrict__ h,
        const _Float16* __restrict__ Whi, const _Float16* __restrict__ Wlo,
        const float* __restrict__ bias, float* __restrict__ resid) {
    __shared__ _Float16 Ah[128][40], Al[128][40], Bh[64][40], Bl[64][40];
    int tid = threadIdx.x;
    int lane = tid & 63, wave = tid >> 6;
    int wm = wave >> 1, wn = wave & 1;
    int quad = lane >> 4, l15 = lane & 15;
    int m0 = blockIdx.x * 128, n0 = blockIdx.y * 64;
    int bb = m0 >> 9, t0 = m0 & 511;

    floatx4 acch[4][2], accx[4][2];
#pragma unroll
    for (int i = 0; i < 4; ++i)
#pragma unroll
        for (int j = 0; j < 2; ++j)
#pragma unroll
            for (int r = 0; r < 4; ++r) { acch[i][j][r] = 0.f; accx[i][j][r] = 0.f; }

    for (int kb = 0; kb < 1536; kb += 32) {
        int ktap = kb >> 9;          // 0,1,2 — 32 | 512 keeps K-tile in one tap
        int din0 = kb & 511;
        // stage A (128x32) from h fp32 rows t0+row+ktap-1, zero-pad at batch edges
#pragma unroll
        for (int r = 0; r < 4; ++r) {
            int t2 = tid + r * 256;
            int row = t2 >> 3, c4 = t2 & 7;
            int tt = t0 + row + ktap - 1;
            half4v hh, ll;
            if ((unsigned)tt < 512u) {
                float4 v = *(const float4*)(h + (((size_t)(bb << 9) + tt) << 9) + din0 + c4 * 4);
                HL e0 = split2(v.x), e1 = split2(v.y), e2 = split2(v.z), e3 = split2(v.w);
                hh[0] = e0.h; hh[1] = e1.h; hh[2] = e2.h; hh[3] = e3.h;
                ll[0] = e0.l; ll[1] = e1.l; ll[2] = e2.l; ll[3] = e3.l;
            } else {
                hh = (half4v)(_Float16)0.f;
                ll = (half4v)(_Float16)0.f;
            }
            *(half4v*)&Ah[row][c4 * 4] = hh;
            *(half4v*)&Al[row][c4 * 4] = ll;
        }
        // stage B (64x32) from pre-split W: 16B copies
        {
            int row = tid >> 2, c = tid & 3;
            *(int4*)&Bh[row][c * 8] = *(const int4*)(Whi + (size_t)(n0 + row) * 1536 + kb + c * 8);
            *(int4*)&Bl[row][c * 8] = *(const int4*)(Wlo + (size_t)(n0 + row) * 1536 + kb + c * 8);
        }
        __syncthreads();
        half8v afh[4], afl[4], bfh[2], bfl[2];
#pragma unroll
        for (int tm = 0; tm < 4; ++tm) {
            afh[tm] = *(const half8v*)&Ah[wm * 64 + tm * 16 + l15][quad * 8];
            afl[tm] = *(const half8v*)&Al[wm * 64 + tm * 16 + l15][quad * 8];
        }
#pragma unroll
        for (int tn = 0; tn < 2; ++tn) {
            bfh[tn] = *(const half8v*)&Bh[wn * 32 + tn * 16 + l15][quad * 8];
            bfl[tn] = *(const half8v*)&Bl[wn * 32 + tn * 16 + l15][quad * 8];
        }
#pragma unroll
        for (int tm = 0; tm < 4; ++tm)
#pragma unroll
            for (int tn = 0; tn < 2; ++tn) {
                acch[tm][tn] = __builtin_amdgcn_mfma_f32_16x16x32_f16(afh[tm], bfh[tn], acch[tm][tn], 0, 0, 0);
                accx[tm][tn] = __builtin_amdgcn_mfma_f32_16x16x32_f16(afh[tm], bfl[tn], accx[tm][tn], 0, 0, 0);
                accx[tm][tn] = __builtin_amdgcn_mfma_f32_16x16x32_f16(afl[tm], bfh[tn], accx[tm][tn], 0, 0, 0);
            }
        __syncthreads();
    }
    float bi[2];
    bi[0] = bias[n0 + wn * 32 + l15];
    bi[1] = bias[n0 + wn * 32 + 16 + l15];
#pragma unroll
    for (int tm = 0; tm < 4; ++tm)
#pragma unroll
        for (int reg = 0; reg < 4; ++reg) {
            int m = m0 + wm * 64 + tm * 16 + quad * 4 + reg;
#pragma unroll
            for (int tn = 0; tn < 2; ++tn) {
                int n = n0 + wn * 32 + tn * 16 + l15;
                size_t off = (size_t)m * 512 + n;
                float c = acch[tm][tn][reg] + accx[tm][tn][reg] * (1.0f / 4096.0f);
                resid[off] -= 0.5f * h[off] + 0.5f * (c + bi[tn]);
            }
        }
}

__global__ __launch_bounds__(256) void k_final(const float* __restrict__ x,
        const float* __restrict__ resid, float* __restrict__ out) {
    int gid = blockIdx.x * 256 + threadIdx.x;
    float4 xv = ((const float4*)x)[gid];
    float4 rv = ((const float4*)resid)[gid];
    float4 o;
    o.x = xv.x - rv.x; o.y = xv.y - rv.y; o.z = xv.z - rv.z; o.w = xv.w - rv.w;
    ((float4*)out)[gid] = o;
}

extern "C" void kernel_launch(void* const* d_in, const int* in_sizes, int n_in,
                              void* d_out, int out_size, void* d_ws, size_t ws_size,
                              hipStream_t stream) {
    const float* x     = (const float*)d_in[0];
    const float* embed = (const float*)d_in[1];
    const float* pw    = (const float*)d_in[2];
    const float* pb    = (const float*)d_in[3];
    float* out = (float*)d_out;

    // ws layout: resid 16MB | zbuf 8MB | W_hi 6MB | W_lo 6MB | esq | minbuf  (~36.1 MB)
    float* resid = (float*)d_ws;
    float* zbuf  = resid + 4194304;
    _Float16* Whi = (_Float16*)(zbuf + 2097152);
    _Float16* Wlo = Whi + 3145728;
    float* esq   = (float*)(Wlo + 3145728);
    unsigned long long* minbuf = (unsigned long long*)(esq + 4096);

    k_esq<<<1024, 256, 0, stream>>>(embed, esq);
    k_copy<<<4096, 256, 0, stream>>>(x, resid);
    k_split_w<<<12288, 256, 0, stream>>>(pw, Whi, Wlo);

    const int SCv[10] = {1, 2, 4, 8, 16, 32, 64, 128, 256, 512};
    // PHI_IDX with float64-ulp tie-breaks at si=2 and si=7 (verified round 2)
    const int PIv[10] = {0, 0, 1, 1, 1, 2, 2, 3, 3, 3};
    for (int si = 0; si < 10; ++si) {
        int s = SCv[si];
        int M = 16 * s;
        const float* zptr;
        if (s < 512) {
            int lg = __builtin_ctz((unsigned)s);
            k_zmean<<<(16 * s * 512) / 256, 256, 0, stream>>>(resid, zbuf, s, lg);
            zptr = zbuf;
        } else {
            zptr = resid;   // block size 1: z == residual
        }
        (void)hipMemsetAsync(minbuf, 0xFF, (size_t)M * 8, stream);
        if (s >= 16)
            k_dist_mfma<<<dim3(M / 128, 64), 256, 0, stream>>>(zptr, embed, esq, minbuf);
        else
            k_dist_small<<<dim3((M + 31) / 32, 64), 256, 0, stream>>>(zptr, embed, esq, minbuf, M);
        k_upsample<<<4096, 256, 0, stream>>>(minbuf, embed, out, s, (float)s / 512.0f);
        k_conv_mfma<<<dim3(64, 8), 256, 0, stream>>>(out, Whi + (size_t)PIv[si] * 512 * 1536,
                                                     Wlo + (size_t)PIv[si] * 512 * 1536,
                                                     pb + PIv[si] * 512, resid);
    }
    k_final<<<4096, 256, 0, stream>>>(x, resid, out);
}

// Round 5
// 1061.061 us; speedup vs baseline: 2.9296x; 1.6229x over previous
//
#include <hip/hip_runtime.h>

// Multiscale Residual VQ (VAR-style), MI355X gfx950.
// Round 5: (a) pre-split fp16 hi/lo for embed/z/W (kills in-loop split VALU),
// (b) conv-via-coarse-u trick for s<=128 (conv(Upsample(q)) = lerp of W_tap q,
//     cutting issued conv FLOPs ~5x), direct gather/interp conv for s in {256,512},
// (c) 128x128 blocks, 4 waves x (64x64), dual-acc split-fp16 (hi*hi + cross/4096).
// Dist dots bit-identical to round 4 (same MFMA shapes/K-order) -> no flip risk.

#define ND 512
#define NCB 4096

typedef _Float16 half8v __attribute__((ext_vector_type(8)));
typedef float floatx4 __attribute__((ext_vector_type(4)));

struct HL { _Float16 h, l; };

__device__ __forceinline__ HL split2(float v) {
    HL r;
    r.h = (_Float16)v;
    r.l = (_Float16)((v - (float)r.h) * 4096.0f);
    return r;
}

__device__ __forceinline__ unsigned long long pack_dist(float d, int n) {
    unsigned u = __float_as_uint(d);
    u = (u & 0x80000000u) ? ~u : (u | 0x80000000u);   // monotone total order
    return ((unsigned long long)u << 32) | (unsigned)n; // tie -> lowest idx
}

// e_sq[c] = sum_d embed[c,d]^2, fp64 accumulate
__global__ __launch_bounds__(256) void k_esq(const float* __restrict__ embed,
                                             float* __restrict__ esq) {
    int c = blockIdx.x * 4 + (threadIdx.x >> 6);
    int lane = threadIdx.x & 63;
    const float* row = embed + (size_t)c * ND;
    double acc = 0.0;
#pragma unroll
    for (int i = 0; i < ND / 64; ++i) {
        float v = row[lane + i * 64];
        acc += (double)v * (double)v;
    }
#pragma unroll
    for (int off = 32; off > 0; off >>= 1) acc += __shfl_down(acc, off, 64);
    if (lane == 0) esq[c] = (float)acc;
}

__global__ __launch_bounds__(256) void k_copy(const float* __restrict__ src,
                                              float* __restrict__ dst) {
    int gid = blockIdx.x * 256 + threadIdx.x;
    ((float4*)dst)[gid] = ((const float4*)src)[gid];
}

// embed -> ehi/elo (4096x512 halves)
__global__ __launch_bounds__(256) void k_split_embed(const float* __restrict__ embed,
        _Float16* __restrict__ eh, _Float16* __restrict__ el) {
    int gid = blockIdx.x * 256 + threadIdx.x;       // 524288 float4s
    float4 v = ((const float4*)embed)[gid];
    HL a = split2(v.x), b = split2(v.y), c = split2(v.z), d = split2(v.w);
    _Float16* ph = eh + (size_t)gid * 4;
    _Float16* pl = el + (size_t)gid * 4;
    ph[0] = a.h; ph[1] = b.h; ph[2] = c.h; ph[3] = d.h;
    pl[0] = a.l; pl[1] = b.l; pl[2] = c.l; pl[3] = d.l;
}

// Wt2[kp][tap*512+dout][din] hi/lo from pw[kp][dout][din][tap]; output-indexed
__global__ __launch_bounds__(256) void k_split_w(const float* __restrict__ pw,
        _Float16* __restrict__ wh, _Float16* __restrict__ wl) {
    int gid = blockIdx.x * 256 + threadIdx.x;       // 4*1536*512 = 3,145,728
    int din = gid & 511;
    int nn = (gid >> 9) % 1536;
    int kp = gid / (512 * 1536);
    int tap = nn >> 9;
    int dout = nn & 511;
    float v = pw[(((size_t)(kp * 512 + dout) * 512) + din) * 3 + tap];
    HL r = split2(v);
    wh[gid] = r.h;
    wl[gid] = r.l;
}

// z[b,j,d] = block mean of residual (fp64 acc) -> split halves zh/zl
__global__ __launch_bounds__(256) void k_zmean(const float* __restrict__ resid,
        _Float16* __restrict__ zh, _Float16* __restrict__ zl, int s, int lg) {
    int gid = blockIdx.x * 256 + threadIdx.x;       // 16*s*512 threads
    int d = gid & 511;
    int j = (gid >> 9) & (s - 1);
    int b = gid >> (9 + lg);
    int r = 512 >> lg;
    const float* p = resid + ((size_t)((b << 9) + (j << (9 - lg))) << 9) + d;
    double acc = 0.0;
#pragma unroll 4
    for (int m = 0; m < r; ++m) acc += (double)p[(size_t)m * ND];
    float v = (float)(acc * (1.0 / (double)r));
    HL hl = split2(v);
    zh[gid] = hl.h;
    zl[gid] = hl.l;
}

// ---------------- dist: block 128m x 128n, 4 waves (2x2) each 64x64 ----------------
__global__ __launch_bounds__(256, 2) void k_dist_mfma(const _Float16* __restrict__ zh,
        const _Float16* __restrict__ zl, const _Float16* __restrict__ eh,
        const _Float16* __restrict__ el, const float* __restrict__ esq,
        unsigned long long* __restrict__ minbuf, int M) {
    __shared__ _Float16 Ah[128][40], Al[128][40], Bh[128][40], Bl[128][40];
    __shared__ unsigned long long packs[128][2];
    int tid = threadIdx.x;
    int lane = tid & 63, wave = tid >> 6;
    int wm = wave >> 1, wn = wave & 1;
    int quad = lane >> 4, l15 = lane & 15;
    int m0 = blockIdx.x * 128, n0 = blockIdx.y * 128;

    floatx4 acch[4][4], accx[4][4];
#pragma unroll
    for (int i = 0; i < 4; ++i)
#pragma unroll
        for (int j = 0; j < 4; ++j)
#pragma unroll
            for (int r = 0; r < 4; ++r) { acch[i][j][r] = 0.f; accx[i][j][r] = 0.f; }

    for (int kb = 0; kb < 512; kb += 32) {
#pragma unroll
        for (int r = 0; r < 2; ++r) {
            int c = tid + r * 256;
            int row = c >> 2, c8 = c & 3;
            int arow = m0 + row; if (arow >= M) arow = M - 1;
            *(int4*)&Ah[row][c8 * 8] = *(const int4*)(zh + (size_t)arow * 512 + kb + c8 * 8);
            *(int4*)&Al[row][c8 * 8] = *(const int4*)(zl + (size_t)arow * 512 + kb + c8 * 8);
            int brow = n0 + row;
            *(int4*)&Bh[row][c8 * 8] = *(const int4*)(eh + (size_t)brow * 512 + kb + c8 * 8);
            *(int4*)&Bl[row][c8 * 8] = *(const int4*)(el + (size_t)brow * 512 + kb + c8 * 8);
        }
        __syncthreads();
        half8v afh[4], afl[4], bfh[4], bfl[4];
#pragma unroll
        for (int tm = 0; tm < 4; ++tm) {
            afh[tm] = *(const half8v*)&Ah[wm * 64 + tm * 16 + l15][quad * 8];
            afl[tm] = *(const half8v*)&Al[wm * 64 + tm * 16 + l15][quad * 8];
        }
#pragma unroll
        for (int tn = 0; tn < 4; ++tn) {
            bfh[tn] = *(const half8v*)&Bh[wn * 64 + tn * 16 + l15][quad * 8];
            bfl[tn] = *(const half8v*)&Bl[wn * 64 + tn * 16 + l15][quad * 8];
        }
#pragma unroll
        for (int tm = 0; tm < 4; ++tm)
#pragma unroll
            for (int tn = 0; tn < 4; ++tn) {
                acch[tm][tn] = __builtin_amdgcn_mfma_f32_16x16x32_f16(afh[tm], bfh[tn], acch[tm][tn], 0, 0, 0);
                accx[tm][tn] = __builtin_amdgcn_mfma_f32_16x16x32_f16(afh[tm], bfl[tn], accx[tm][tn], 0, 0, 0);
                accx[tm][tn] = __builtin_amdgcn_mfma_f32_16x16x32_f16(afl[tm], bfh[tn], accx[tm][tn], 0, 0, 0);
            }
        __syncthreads();
    }
    float es[4];
#pragma unroll
    for (int tn = 0; tn < 4; ++tn) es[tn] = esq[n0 + wn * 64 + tn * 16 + l15];
#pragma unroll
    for (int tm = 0; tm < 4; ++tm)
#pragma unroll
        for (int reg = 0; reg < 4; ++reg) {
            unsigned long long best = ~0ull;
#pragma unroll
            for (int tn = 0; tn < 4; ++tn) {
                float dot = acch[tm][tn][reg] + accx[tm][tn][reg] * (1.0f / 4096.0f);
                int n = n0 + wn * 64 + tn * 16 + l15;
                float dd = fmaf(-2.f, dot, es[tn]);
                unsigned long long p = pack_dist(dd, n);
                best = p < best ? p : best;
            }
#pragma unroll
            for (int off = 1; off < 16; off <<= 1) {
                unsigned long long q = __shfl_xor(best, off, 64);
                best = q < best ? q : best;
            }
            if (l15 == 0) packs[wm * 64 + tm * 16 + quad * 4 + reg][wn] = best;
        }
    __syncthreads();
    if (tid < 128 && m0 + tid < M) {
        unsigned long long b0 = packs[tid][0], b1 = packs[tid][1];
        atomicMin(&minbuf[m0 + tid], b0 < b1 ? b0 : b1);
    }
}

// ---------------- phi: u[m][tap*512+dout] = (W_tap q_m)[dout], m = b*s+j ----------------
// GEMM [M x 512] x [512 x 1536]; A rows gathered from pre-split embed by idx.
__global__ __launch_bounds__(256, 2) void k_phi(const _Float16* __restrict__ eh,
        const _Float16* __restrict__ el, const _Float16* __restrict__ wh,
        const _Float16* __restrict__ wl, const unsigned long long* __restrict__ minbuf,
        float* __restrict__ u, int M) {
    __shared__ _Float16 Ah[128][40], Al[128][40], Bh[128][40], Bl[128][40];
    __shared__ int idxs[128];
    int tid = threadIdx.x;
    int lane = tid & 63, wave = tid >> 6;
    int wm = wave >> 1, wn = wave & 1;
    int quad = lane >> 4, l15 = lane & 15;
    int m0 = blockIdx.x * 128, n0 = blockIdx.y * 128;
    if (tid < 128) {
        int m = m0 + tid; if (m >= M) m = M - 1;
        idxs[tid] = (int)(unsigned)minbuf[m];
    }
    floatx4 acch[4][4], accx[4][4];
#pragma unroll
    for (int i = 0; i < 4; ++i)
#pragma unroll
        for (int j = 0; j < 4; ++j)
#pragma unroll
            for (int r = 0; r < 4; ++r) { acch[i][j][r] = 0.f; accx[i][j][r] = 0.f; }
    __syncthreads();
    for (int kb = 0; kb < 512; kb += 32) {
#pragma unroll
        for (int r = 0; r < 2; ++r) {
            int c = tid + r * 256;
            int row = c >> 2, c8 = c & 3;
            int code = idxs[row];
            *(int4*)&Ah[row][c8 * 8] = *(const int4*)(eh + (size_t)code * 512 + kb + c8 * 8);
            *(int4*)&Al[row][c8 * 8] = *(const int4*)(el + (size_t)code * 512 + kb + c8 * 8);
            int brow = n0 + row;
            *(int4*)&Bh[row][c8 * 8] = *(const int4*)(wh + (size_t)brow * 512 + kb + c8 * 8);
            *(int4*)&Bl[row][c8 * 8] = *(const int4*)(wl + (size_t)brow * 512 + kb + c8 * 8);
        }
        __syncthreads();
        half8v afh[4], afl[4], bfh[4], bfl[4];
#pragma unroll
        for (int tm = 0; tm < 4; ++tm) {
            afh[tm] = *(const half8v*)&Ah[wm * 64 + tm * 16 + l15][quad * 8];
            afl[tm] = *(const half8v*)&Al[wm * 64 + tm * 16 + l15][quad * 8];
        }
#pragma unroll
        for (int tn = 0; tn < 4; ++tn) {
            bfh[tn] = *(const half8v*)&Bh[wn * 64 + tn * 16 + l15][quad * 8];
            bfl[tn] = *(const half8v*)&Bl[wn * 64 + tn * 16 + l15][quad * 8];
        }
#pragma unroll
        for (int tm = 0; tm < 4; ++tm)
#pragma unroll
            for (int tn = 0; tn < 4; ++tn) {
                acch[tm][tn] = __builtin_amdgcn_mfma_f32_16x16x32_f16(afh[tm], bfh[tn], acch[tm][tn], 0, 0, 0);
                accx[tm][tn] = __builtin_amdgcn_mfma_f32_16x16x32_f16(afh[tm], bfl[tn], accx[tm][tn], 0, 0, 0);
                accx[tm][tn] = __builtin_amdgcn_mfma_f32_16x16x32_f16(afl[tm], bfh[tn], accx[tm][tn], 0, 0, 0);
            }
        __syncthreads();
    }
#pragma unroll
    for (int tm = 0; tm < 4; ++tm)
#pragma unroll
        for (int reg = 0; reg < 4; ++reg) {
            int m = m0 + wm * 64 + tm * 16 + quad * 4 + reg;
            if (m < M) {
#pragma unroll
                for (int tn = 0; tn < 4; ++tn) {
                    int n = n0 + wn * 64 + tn * 16 + l15;
                    u[(size_t)m * 1536 + n] = acch[tm][tn][reg] + accx[tm][tn][reg] * (1.0f / 4096.0f);
                }
            }
        }
}

// combine (s<=128): resid -= 0.5*h + 0.5*(conv+bias); h = lerp(embed[idx]),
// conv[t] = sum_tap lerp of u[.][tap] at t' = t+tap-1
__global__ __launch_bounds__(256) void k_combine(const float* __restrict__ u,
        const float* __restrict__ embed, const unsigned long long* __restrict__ minbuf,
        const float* __restrict__ bias, float* __restrict__ resid, int s, float scale) {
    int tid = threadIdx.x;
    int m = blockIdx.x * 2 + (tid >> 7);
    int d4 = (tid & 127) << 2;
    int b = m >> 9, t = m & 511;
    int bs = b * s;
    float4 bi = *(const float4*)(bias + d4);
    float uu = ((float)t + 0.5f) * scale - 0.5f;
    float fl = floorf(uu);
    float w = uu - fl;
    int i0 = (int)fl, i1 = i0 + 1;
    i0 = min(max(i0, 0), s - 1);
    i1 = min(max(i1, 0), s - 1);
    int c0 = (int)(unsigned)minbuf[bs + i0];
    int c1 = (int)(unsigned)minbuf[bs + i1];
    float4 e0 = *(const float4*)(embed + (size_t)c0 * 512 + d4);
    float4 e1 = *(const float4*)(embed + (size_t)c1 * 512 + d4);
    float om = 1.0f - w;
    float4 h4;
    h4.x = om * e0.x + w * e1.x; h4.y = om * e0.y + w * e1.y;
    h4.z = om * e0.z + w * e1.z; h4.w = om * e0.w + w * e1.w;
    float4 conv = make_float4(0.f, 0.f, 0.f, 0.f);
#pragma unroll
    for (int tap = 0; tap < 3; ++tap) {
        int tt = t + tap - 1;
        if (tt >= 0 && tt < 512) {
            float uu2 = ((float)tt + 0.5f) * scale - 0.5f;
            float fl2 = floorf(uu2);
            float w2 = uu2 - fl2;
            int j0 = (int)fl2, j1 = j0 + 1;
            j0 = min(max(j0, 0), s - 1);
            j1 = min(max(j1, 0), s - 1);
            float4 a4 = *(const float4*)(u + (size_t)(bs + j0) * 1536 + tap * 512 + d4);
            float4 b4 = *(const float4*)(u + (size_t)(bs + j1) * 1536 + tap * 512 + d4);
            float ow = 1.0f - w2;
            conv.x += ow * a4.x + w2 * b4.x;
            conv.y += ow * a4.y + w2 * b4.y;
            conv.z += ow * a4.z + w2 * b4.z;
            conv.w += ow * a4.w + w2 * b4.w;
        }
    }
    size_t off = (size_t)m * 512 + d4;
    float4 rv = *(float4*)(resid + off);
    rv.x -= 0.5f * h4.x + 0.5f * (conv.x + bi.x);
    rv.y -= 0.5f * h4.y + 0.5f * (conv.y + bi.y);
    rv.z -= 0.5f * h4.z + 0.5f * (conv.z + bi.z);
    rv.w -= 0.5f * h4.w + 0.5f * (conv.w + bi.w);
    *(float4*)(resid + off) = rv;
}

// direct conv (s in {256,512}): GEMM [8192 x 1536(tap,din)] x [1536 x 512(dout)]
// A rows = split(lerp of embed rows at t'=t+tap-1); B = Wt2 rows (tap*512+dout).
// epilogue: resid -= 0.5*h + 0.5*(conv+bias)
__global__ __launch_bounds__(256, 2) void k_conv(const _Float16* __restrict__ eh,
        const _Float16* __restrict__ el, const float* __restrict__ embed,
        const _Float16* __restrict__ wh, const _Float16* __restrict__ wl,
        const float* __restrict__ bias, const unsigned long long* __restrict__ minbuf,
        float* __restrict__ resid, int s, float scale) {
    __shared__ _Float16 Ah[128][40], Al[128][40], Bh[128][40], Bl[128][40];
    __shared__ int c0s[132], c1s[132];
    __shared__ float wws[132];
    int tid = threadIdx.x;
    int lane = tid & 63, wave = tid >> 6;
    int wm = wave >> 1, wn = wave & 1;
    int quad = lane >> 4, l15 = lane & 15;
    int m0 = blockIdx.x * 128, n0 = blockIdx.y * 128;
    int b = m0 >> 9, t0 = m0 & 511, bs = b * s;
    int noint = (s == 512);
    if (tid < 130) {
        int tt = t0 + tid - 1;
        if (tt >= 0 && tt < 512) {
            float uu = ((float)tt + 0.5f) * scale - 0.5f;
            float fl = floorf(uu);
            float w = uu - fl;
            int i0 = (int)fl, i1 = i0 + 1;
            i0 = min(max(i0, 0), s - 1);
            i1 = min(max(i1, 0), s - 1);
            c0s[tid] = (int)(unsigned)minbuf[bs + i0];
            c1s[tid] = (int)(unsigned)minbuf[bs + i1];
            wws[tid] = w;
        } else { c0s[tid] = -1; c1s[tid] = -1; wws[tid] = 0.f; }
    }
    floatx4 acch[4][4], accx[4][4];
#pragma unroll
    for (int i = 0; i < 4; ++i)
#pragma unroll
        for (int j = 0; j < 4; ++j)
#pragma unroll
            for (int r = 0; r < 4; ++r) { acch[i][j][r] = 0.f; accx[i][j][r] = 0.f; }
    __syncthreads();
    for (int kb = 0; kb < 1536; kb += 32) {
        int tap = kb >> 9, din0 = kb & 511;
#pragma unroll
        for (int r = 0; r < 2; ++r) {
            int c = tid + r * 256;
            int row = c >> 2, c8 = c & 3;
            int j = row + tap;
            int cc0 = c0s[j], cc1 = c1s[j];
            half8v hh8, ll8;
            if (cc0 < 0) {
                hh8 = (half8v)(_Float16)0.f;
                ll8 = (half8v)(_Float16)0.f;
                *(half8v*)&Ah[row][c8 * 8] = hh8;
                *(half8v*)&Al[row][c8 * 8] = ll8;
            } else if (noint) {
                *(int4*)&Ah[row][c8 * 8] = *(const int4*)(eh + (size_t)cc0 * 512 + din0 + c8 * 8);
                *(int4*)&Al[row][c8 * 8] = *(const int4*)(el + (size_t)cc0 * 512 + din0 + c8 * 8);
            } else {
                float w = wws[j], ow = 1.0f - w;
                const float* p0 = embed + (size_t)cc0 * 512 + din0 + c8 * 8;
                const float* p1 = embed + (size_t)cc1 * 512 + din0 + c8 * 8;
                float4 a0 = *(const float4*)p0, a1 = *(const float4*)(p0 + 4);
                float4 b0 = *(const float4*)p1, b1 = *(const float4*)(p1 + 4);
                float vals[8];
                vals[0] = ow * a0.x + w * b0.x; vals[1] = ow * a0.y + w * b0.y;
                vals[2] = ow * a0.z + w * b0.z; vals[3] = ow * a0.w + w * b0.w;
                vals[4] = ow * a1.x + w * b1.x; vals[5] = ow * a1.y + w * b1.y;
                vals[6] = ow * a1.z + w * b1.z; vals[7] = ow * a1.w + w * b1.w;
#pragma unroll
                for (int q = 0; q < 8; ++q) {
                    HL hl = split2(vals[q]);
                    hh8[q] = hl.h; ll8[q] = hl.l;
                }
                *(half8v*)&Ah[row][c8 * 8] = hh8;
                *(half8v*)&Al[row][c8 * 8] = ll8;
            }
            int brow = tap * 512 + n0 + row;     // Wt2 row = tap*512 + dout
            *(int4*)&Bh[row][c8 * 8] = *(const int4*)(wh + (size_t)brow * 512 + din0 + c8 * 8);
            *(int4*)&Bl[row][c8 * 8] = *(const int4*)(wl + (size_t)brow * 512 + din0 + c8 * 8);
        }
        __syncthreads();
        half8v afh[4], afl[4], bfh[4], bfl[4];
#pragma unroll
        for (int tm = 0; tm < 4; ++tm) {
            afh[tm] = *(const half8v*)&Ah[wm * 64 + tm * 16 + l15][quad * 8];
            afl[tm] = *(const half8v*)&Al[wm * 64 + tm * 16 + l15][quad * 8];
        }
#pragma unroll
        for (int tn = 0; tn < 4; ++tn) {
            bfh[tn] = *(const half8v*)&Bh[wn * 64 + tn * 16 + l15][quad * 8];
            bfl[tn] = *(const half8v*)&Bl[wn * 64 + tn * 16 + l15][quad * 8];
        }
#pragma unroll
        for (int tm = 0; tm < 4; ++tm)
#pragma unroll
            for (int tn = 0; tn < 4; ++tn) {
                acch[tm][tn] = __builtin_amdgcn_mfma_f32_16x16x32_f16(afh[tm], bfh[tn], acch[tm][tn], 0, 0, 0);
                accx[tm][tn] = __builtin_amdgcn_mfma_f32_16x16x32_f16(afh[tm], bfl[tn], accx[tm][tn], 0, 0, 0);
                accx[tm][tn] = __builtin_amdgcn_mfma_f32_16x16x32_f16(afl[tm], bfh[tn], accx[tm][tn], 0, 0, 0);
            }
        __syncthreads();
    }
#pragma unroll
    for (int tm = 0; tm < 4; ++tm)
#pragma unroll
        for (int reg = 0; reg < 4; ++reg) {
            int row = wm * 64 + tm * 16 + quad * 4 + reg;
            int m = m0 + row;
            int jj = row + 1;                  // tap=1 -> t'=t
            int cc0 = c0s[jj], cc1 = c1s[jj];
            float w = wws[jj], ow = 1.0f - w;
#pragma unroll
            for (int tn = 0; tn < 4; ++tn) {
                int n = n0 + wn * 64 + tn * 16 + l15;
                float h = ow * embed[(size_t)cc0 * 512 + n] + w * embed[(size_t)cc1 * 512 + n];
                float val = acch[tm][tn][reg] + accx[tm][tn][reg] * (1.0f / 4096.0f);
                size_t off = (size_t)m * 512 + n;
                resid[off] -= 0.5f * h + 0.5f * (val + bias[n]);
            }
        }
}

__global__ __launch_bounds__(256) void k_final(const float* __restrict__ x,
        const float* __restrict__ resid, float* __restrict__ out) {
    int gid = blockIdx.x * 256 + threadIdx.x;
    float4 xv = ((const float4*)x)[gid];
    float4 rv = ((const float4*)resid)[gid];
    float4 o;
    o.x = xv.x - rv.x; o.y = xv.y - rv.y; o.z = xv.z - rv.z; o.w = xv.w - rv.w;
    ((float4*)out)[gid] = o;
}

extern "C" void kernel_launch(void* const* d_in, const int* in_sizes, int n_in,
                              void* d_out, int out_size, void* d_ws, size_t ws_size,
                              hipStream_t stream) {
    const float* x     = (const float*)d_in[0];
    const float* embed = (const float*)d_in[1];
    const float* pw    = (const float*)d_in[2];
    const float* pb    = (const float*)d_in[3];
    float* out = (float*)d_out;

    // ws layout (floats), ~54.6 MB total:
    // resid 16MB | U 16MB (zh/zl halves; u<=12.6MB aliases after dist) |
    // ehi/elo 8MB | Wt2 hi/lo 12MB | esq | minbuf
    float* resid = (float*)d_ws;
    float* Ubase = resid + 4194304;
    _Float16* zh = (_Float16*)Ubase;
    _Float16* zl = zh + 4194304;
    float* u = Ubase;
    _Float16* ehi = (_Float16*)(Ubase + 4194304);
    _Float16* elo = ehi + 2097152;
    _Float16* whi = elo + 2097152;
    _Float16* wlo = whi + 3145728;
    float* esq = (float*)(wlo + 3145728);
    unsigned long long* minbuf = (unsigned long long*)(esq + 4096);

    k_esq<<<1024, 256, 0, stream>>>(embed, esq);
    k_split_embed<<<2048, 256, 0, stream>>>(embed, ehi, elo);
    k_split_w<<<12288, 256, 0, stream>>>(pw, whi, wlo);
    k_copy<<<4096, 256, 0, stream>>>(x, resid);

    const int SCv[10] = {1, 2, 4, 8, 16, 32, 64, 128, 256, 512};
    // PHI_IDX with float64-ulp tie-breaks at si=2 and si=7 (verified round 2)
    const int PIv[10] = {0, 0, 1, 1, 1, 2, 2, 3, 3, 3};
    for (int si = 0; si < 10; ++si) {
        int s = SCv[si];
        int M = 16 * s;
        int kp = PIv[si];
        int lg = __builtin_ctz((unsigned)s);
        float scale = (float)s / 512.0f;
        k_zmean<<<(M * 512) / 256, 256, 0, stream>>>(resid, zh, zl, s, lg);
        (void)hipMemsetAsync(minbuf, 0xFF, (size_t)M * 8, stream);
        k_dist_mfma<<<dim3((M + 127) / 128, 32), 256, 0, stream>>>(zh, zl, ehi, elo, esq, minbuf, M);
        if (s <= 128) {
            k_phi<<<dim3((M + 127) / 128, 12), 256, 0, stream>>>(ehi, elo,
                    whi + (size_t)kp * 1536 * 512, wlo + (size_t)kp * 1536 * 512, minbuf, u, M);
            k_combine<<<4096, 256, 0, stream>>>(u, embed, minbuf, pb + kp * 512, resid, s, scale);
        } else {
            k_conv<<<dim3(64, 4), 256, 0, stream>>>(ehi, elo, embed,
                    whi + (size_t)kp * 1536 * 512, wlo + (size_t)kp * 1536 * 512,
                    pb + kp * 512, minbuf, resid, s, scale);
        }
    }
    k_final<<<4096, 256, 0, stream>>>(x, resid, out);
}